// Round 5
// baseline (931.915 us; speedup 1.0000x reference)
//
#include <hip/hip_runtime.h>
#include <hip/hip_bf16.h>
#include <math.h>

typedef __bf16 bf16_t;
typedef __bf16 bf16x8 __attribute__((ext_vector_type(8)));
typedef float f32x4 __attribute__((ext_vector_type(4)));

// ---------------------------------------------------------------------------
// Problem constants: B=4, H=64, W=128, C=512, F=1024, WS=4, SS=2, NH=8, hd=64.
// M = 32768 token rows. 2048 windows total.
// ---------------------------------------------------------------------------

#define X1_OFF   0u            // x1 fp32 residual [32768,512] = 64 MB
#define XW_OFF   67108864u     // xw -> O -> h2 (bf16, 32 MB)
#define QKV_OFF  100663296u    // qkv -> gelu-out a (bf16, 96 MB)
#define WQ_OFF   201326592u
#define WP_OFF   202899456u
#define W1_OFF   203423744u
#define W2_OFF   204472320u
#define SV_OFF   205520896u
#define FLAG_OFF 205545472u
// SV float offsets: g1=0 be1=512 bq=1024 bp=2560 g2=3072 be2=3584 b1=4096
//                   b2=5120 rpb=5632 (end 6024)

__device__ __forceinline__ int perm_row(int r) {
    int b   = r >> 13;
    int rem = r & 8191;
    int w   = rem >> 4;
    int n   = rem & 15;
    int wy  = w >> 5, wx = w & 31;
    int y   = wy * 4 + (n >> 2);
    int x   = wx * 4 + (n & 3);
    int ys  = (y + 2) & 63;
    int xs  = (x + 2) & 127;
    return (b << 13) + (ys << 7) + xs;
}

// global->LDS direct load, 16 B per lane: per-lane global addr, wave-uniform
// LDS base; HW scatters lane i -> base + i*16.
__device__ __forceinline__ void gld16(const void* g, void* l) {
    __builtin_amdgcn_global_load_lds(
        (const __attribute__((address_space(1))) unsigned int*)(unsigned long long)(uintptr_t)g,
        (__attribute__((address_space(3))) unsigned int*)(unsigned int)(uintptr_t)l,
        16, 0, 0);
}

// ---------------- dtype probe: 1 = fp32 source, 0 = bf16 source ----------------
__global__ __launch_bounds__(256) void k_probe(const unsigned short* __restrict__ x,
                                               int n, int* __restrict__ flag) {
    __shared__ int cnt;
    if (threadIdx.x == 0) cnt = 0;
    __syncthreads();
    int c = 0;
    for (int i = threadIdx.x; i < n; i += 256) {
        int e = (x[i] >> 7) & 0xFF;
        if (e >= 0xC0) c++;
    }
    atomicAdd(&cnt, c);
    __syncthreads();
    if (threadIdx.x == 0) *flag = (cnt > 8) ? 1 : 0;
}

// ---------------- weight / small-vector normalization ----------------
__global__ __launch_bounds__(256) void k_cvt_bf16(const void* __restrict__ src,
                                                  bf16_t* __restrict__ dst, int n,
                                                  const int* __restrict__ flag) {
    int i = blockIdx.x * 256 + threadIdx.x;
    if (i >= n) return;
    dst[i] = (*flag) ? (bf16_t)((const float*)src)[i] : ((const bf16_t*)src)[i];
}

__global__ __launch_bounds__(256) void k_cvt_small(
        const void* g1, const void* be1, const void* bq, const void* bp,
        const void* g2, const void* be2, const void* b1, const void* b2,
        const void* rpb, float* __restrict__ dst, const int* __restrict__ flag) {
    int i = blockIdx.x * 256 + threadIdx.x;
    const void* src; int off;
    if      (i < 512)  { src = g1;  off = i; }
    else if (i < 1024) { src = be1; off = i - 512; }
    else if (i < 2560) { src = bq;  off = i - 1024; }
    else if (i < 3072) { src = bp;  off = i - 2560; }
    else if (i < 3584) { src = g2;  off = i - 3072; }
    else if (i < 4096) { src = be2; off = i - 3584; }
    else if (i < 5120) { src = b1;  off = i - 4096; }
    else if (i < 5632) { src = b2;  off = i - 5120; }
    else if (i < 6024) { src = rpb; off = i - 5632; }
    else return;
    dst[i] = (*flag) ? ((const float*)src)[off] : (float)((const bf16_t*)src)[off];
}

// ---------------- Kernel 1: LN1 + shift + window partition ----------------
__global__ __launch_bounds__(256) void k_ln1(const void* __restrict__ x,
                                             const float* __restrict__ g,
                                             const float* __restrict__ be,
                                             bf16_t* __restrict__ xw,
                                             const int* __restrict__ flag) {
    int r    = blockIdx.x * 4 + (threadIdx.x >> 6);
    int lane = threadIdx.x & 63;
    int f    = *flag;
    long ro  = (long)perm_row(r) * 512;
    const float*  x32 = (const float*)x + ro;
    const bf16_t* x16 = (const bf16_t*)x + ro;
    int base = lane * 8;
    float v[8];
    float s = 0.f, ss = 0.f;
#pragma unroll
    for (int j = 0; j < 8; j++) {
        float t = f ? x32[base + j] : (float)x16[base + j];
        v[j] = t; s += t; ss += t * t;
    }
#pragma unroll
    for (int off = 32; off; off >>= 1) {
        s  += __shfl_down(s,  off, 64);
        ss += __shfl_down(ss, off, 64);
    }
    s  = __shfl(s, 0, 64);
    ss = __shfl(ss, 0, 64);
    float m   = s * (1.f / 512.f);
    float var = ss * (1.f / 512.f) - m * m;
    float inv = rsqrtf(var + 1e-5f);
    bf16_t* orow = xw + (long)r * 512;
#pragma unroll
    for (int j = 0; j < 8; j++)
        orow[base + j] = (bf16_t)((v[j] - m) * inv * g[base + j] + be[base + j]);
}

// ---------------- Kernel 5: LN2 ----------------
__global__ __launch_bounds__(256) void k_ln2(const float* __restrict__ x1,
                                             const float* __restrict__ g,
                                             const float* __restrict__ be,
                                             bf16_t* __restrict__ h2) {
    int r    = blockIdx.x * 4 + (threadIdx.x >> 6);
    int lane = threadIdx.x & 63;
    const float* xr = x1 + (long)r * 512;
    int base = lane * 8;
    float v[8];
    float s = 0.f, ss = 0.f;
#pragma unroll
    for (int j = 0; j < 8; j++) {
        float t = xr[base + j];
        v[j] = t; s += t; ss += t * t;
    }
#pragma unroll
    for (int off = 32; off; off >>= 1) {
        s  += __shfl_down(s,  off, 64);
        ss += __shfl_down(ss, off, 64);
    }
    s  = __shfl(s, 0, 64);
    ss = __shfl(ss, 0, 64);
    float m   = s * (1.f / 512.f);
    float var = ss * (1.f / 512.f) - m * m;
    float inv = rsqrtf(var + 1e-5f);
    bf16_t* orow = h2 + (long)r * 512;
#pragma unroll
    for (int j = 0; j < 8; j++)
        orow[base + j] = (bf16_t)((v[j] - m) * inv * g[base + j] + be[base + j]);
}

// ---------------- B-resident GEMM: zero barriers in the K-loop -------------
// C = A @ W^T. A:[M,K] bf16 rm (read DIRECT global->VGPR, prefetched),
// W:[N,K] bf16 rm (whole [NTILE,K] tile staged once in LDS, XOR-swizzled
// chunks -> conflict-free ds_read_b128). Block = 128 x NTILE of C, 4 waves
// in 2x2, each a 64 x NTILE/2 quadrant (16x16x32 MFMAs). After the single
// prologue barrier the K-loop has NO syncthreads / vmcnt drains.
// NTILE*KT = 32768 elems = 64 KB LDS for all shapes (K=512:NTILE=64,
// K=1024:NTILE=32). XCD swizzle: id%8 == row-stripe%8 -> A L2 locality.
// EPI: 0=bias->bf16  1=proj: x1[perm]=x+acc+bias (fp32)  2=bias+GELU->bf16
//      3=fc2: out=x1+acc+bias (flag dtype)
template<int EPI, int NTILE, int KT>
__global__ __launch_bounds__(256) void k_gemm_bres(const bf16_t* __restrict__ A,
                                                   const bf16_t* __restrict__ Wt,
                                                   const float* __restrict__ bias,
                                                   void* __restrict__ out,
                                                   const void* __restrict__ res,
                                                   const int* __restrict__ flag,
                                                   int N) {
    constexpr int NF  = NTILE / 32;   // B-frags per wave per k-step (2 or 1)
    constexpr int CPR = KT / 8;       // 16B chunks per B row (64 or 128)
    __shared__ bf16_t sB[NTILE * KT]; // 64 KB

    int tid = threadIdx.x, lane = tid & 63, wv = tid >> 6;
    int nbx = N / NTILE;
    int id  = blockIdx.x;
    int xb  = (id >> 3) % nbx;
    int yb  = ((id >> 3) / nbx) * 8 + (id & 7);
    int m0  = yb << 7;
    int n0  = xb * NTILE;

    // ---- prologue: stage the whole B tile (4096 chunks, 16 per thread) ----
#pragma unroll
    for (int j = 0; j < 16; j++) {
        int c   = j * 256 + tid;
        int row = c / CPR, p = c % CPR;
        const bf16_t* g = Wt + (long)(n0 + row) * KT + (long)((p ^ (row & 7)) << 3);
        gld16(g, (char*)sB + j * 4096 + wv * 1024);
    }
    __syncthreads();   // the ONLY barrier

    int rr = lane & 15, quad = lane >> 4;
    int wm = (wv >> 1) * 64, wn = (wv & 1) * (NTILE / 2);

    const bf16_t* pA = A + (long)(m0 + wm + rr) * KT + quad * 8;

    f32x4 acc[4][NF];
#pragma unroll
    for (int mi = 0; mi < 4; mi++)
#pragma unroll
        for (int ni = 0; ni < NF; ni++) { f32x4 z = {0.f,0.f,0.f,0.f}; acc[mi][ni] = z; }

    bf16x8 afn[4];
#pragma unroll
    for (int mi = 0; mi < 4; mi++) afn[mi] = *(const bf16x8*)(pA + (long)mi * 16 * KT);

#pragma unroll 4
    for (int kk = 0; kk < KT / 32; kk++) {
        bf16x8 af[4];
#pragma unroll
        for (int mi = 0; mi < 4; mi++) af[mi] = afn[mi];
        if (kk + 1 < KT / 32) {
#pragma unroll
            for (int mi = 0; mi < 4; mi++)
                afn[mi] = *(const bf16x8*)(pA + (long)mi * 16 * KT + (kk + 1) * 32);
        }
        bf16x8 bg[NF];
#pragma unroll
        for (int ni = 0; ni < NF; ni++) {
            int rl = wn + ni * 16 + rr;
            bg[ni] = *(const bf16x8*)(sB + (long)rl * KT + ((((kk << 2) + quad) ^ (rl & 7)) << 3));
        }
#pragma unroll
        for (int mi = 0; mi < 4; mi++)
#pragma unroll
            for (int ni = 0; ni < NF; ni++)
                acc[mi][ni] = __builtin_amdgcn_mfma_f32_16x16x32_bf16(af[mi], bg[ni], acc[mi][ni], 0, 0, 0);
    }

    int f = (EPI == 1 || EPI == 3) ? *flag : 0;
#pragma unroll
    for (int ni = 0; ni < NF; ni++) {
        int col  = n0 + wn + ni * 16 + rr;
        float bb = bias[col];
#pragma unroll
        for (int mi = 0; mi < 4; mi++) {
#pragma unroll
            for (int i = 0; i < 4; i++) {
                int row  = m0 + wm + mi * 16 + quad * 4 + i;
                float v  = acc[mi][ni][i] + bb;
                if (EPI == 0) {
                    ((bf16_t*)out)[(long)row * N + col] = (bf16_t)v;
                } else if (EPI == 1) {
                    long o   = (long)perm_row(row) * 512 + col;
                    float xv = f ? ((const float*)res)[o] : (float)((const bf16_t*)res)[o];
                    ((float*)out)[o] = xv + v;
                } else if (EPI == 2) {
                    float ge = 0.5f * v * (1.f + erff(v * 0.70710678118654752f));
                    ((bf16_t*)out)[(long)row * N + col] = (bf16_t)ge;
                } else {
                    long o   = (long)row * 512 + col;
                    float vv = ((const float*)res)[o] + v;
                    if (f) ((float*)out)[o] = vv;
                    else   ((bf16_t*)out)[o] = (bf16_t)vv;
                }
            }
        }
    }
}

// ---------------- Kernel 3: windowed attention ----------------
__global__ __launch_bounds__(256) void k_attn(const bf16_t* __restrict__ qkv,
                                              const float* __restrict__ rpb,
                                              bf16_t* __restrict__ O) {
    __shared__ float q[16][68], k[16][68], v[16][68];
    __shared__ float S[16][17];

    int blk = blockIdx.x;
    int h   = blk & 7;
    int w   = blk >> 3;
    int tid = threadIdx.x;

    int n0 = tid >> 4;
    int d0 = (tid & 15) * 4;
    const bf16_t* base = qkv + (long)(w * 16 + n0) * 1536 + h * 64 + d0;
#pragma unroll
    for (int j = 0; j < 4; j++) {
        q[n0][d0 + j] = (float)base[j] * 0.125f;
        k[n0][d0 + j] = (float)base[512 + j];
        v[n0][d0 + j] = (float)base[1024 + j];
    }
    __syncthreads();

    int i = tid >> 4, j = tid & 15;
    float s = 0.f;
#pragma unroll
    for (int d = 0; d < 64; d++) s += q[i][d] * k[j][d];

    int iy = i >> 2, ix = i & 3, jy = j >> 2, jx = j & 3;
    s += rpb[((iy - jy + 3) * 7 + (ix - jx + 3)) * 8 + h];

    int wl = w & 511;
    int wy = wl >> 5, wx = wl & 31;
    int yi = wy * 4 + iy, xi = wx * 4 + ix;
    int yj = wy * 4 + jy, xj = wx * 4 + jx;
    int ri = (yi < 60 ? 0 : (yi < 62 ? 1 : 2)) * 3 + (xi < 124 ? 0 : (xi < 126 ? 1 : 2));
    int rj = (yj < 60 ? 0 : (yj < 62 ? 1 : 2)) * 3 + (xj < 124 ? 0 : (xj < 126 ? 1 : 2));
    if (ri != rj) s -= 100.f;
    S[i][j] = s;
    __syncthreads();

    if (tid < 16) {
        float mx = -1e30f;
#pragma unroll
        for (int c = 0; c < 16; c++) mx = fmaxf(mx, S[tid][c]);
        float sum = 0.f;
#pragma unroll
        for (int c = 0; c < 16; c++) { float e = expf(S[tid][c] - mx); S[tid][c] = e; sum += e; }
        float invs = 1.f / sum;
#pragma unroll
        for (int c = 0; c < 16; c++) S[tid][c] *= invs;
    }
    __syncthreads();

#pragma unroll
    for (int t = 0; t < 4; t++) {
        int e  = tid + t * 256;
        int oi = e >> 6, od = e & 63;
        float acc = 0.f;
#pragma unroll
        for (int c = 0; c < 16; c++) acc += S[oi][c] * v[c][od];
        O[(long)(w * 16 + oi) * 512 + h * 64 + od] = (bf16_t)acc;
    }
}

// ---------------------------------------------------------------------------
extern "C" void kernel_launch(void* const* d_in, const int* in_sizes, int n_in,
                              void* d_out, int out_size, void* d_ws, size_t ws_size,
                              hipStream_t stream) {
    char* ws = (char*)d_ws;
    float*  x1   = (float*)(ws + X1_OFF);
    bf16_t* xw   = (bf16_t*)(ws + XW_OFF);    // xw -> O -> h2
    bf16_t* qkv  = (bf16_t*)(ws + QKV_OFF);   // qkv -> gelu-out a
    bf16_t* wq_b = (bf16_t*)(ws + WQ_OFF);
    bf16_t* wp_b = (bf16_t*)(ws + WP_OFF);
    bf16_t* w1_b = (bf16_t*)(ws + W1_OFF);
    bf16_t* w2_b = (bf16_t*)(ws + W2_OFF);
    float*  sv   = (float*)(ws + SV_OFF);
    int*    flag = (int*)(ws + FLAG_OFF);

    k_probe<<<1, 256, 0, stream>>>((const unsigned short*)d_in[0], 4096, flag);
    k_cvt_bf16<<<3072, 256, 0, stream>>>(d_in[3],  wq_b, 786432, flag);
    k_cvt_bf16<<<1024, 256, 0, stream>>>(d_in[6],  wp_b, 262144, flag);
    k_cvt_bf16<<<2048, 256, 0, stream>>>(d_in[10], w1_b, 524288, flag);
    k_cvt_bf16<<<2048, 256, 0, stream>>>(d_in[12], w2_b, 524288, flag);
    k_cvt_small<<<24,  256, 0, stream>>>(d_in[1], d_in[2], d_in[4], d_in[7],
                                         d_in[8], d_in[9], d_in[11], d_in[13],
                                         d_in[5], sv, flag);

    k_ln1<<<dim3(8192), dim3(256), 0, stream>>>(d_in[0], sv, sv + 512, xw, flag);
    // qkv: M=32768, N=1536, K=512 -> nbx=24, grid 6144
    k_gemm_bres<0,64,512><<<dim3(6144), dim3(256), 0, stream>>>(xw, wq_b, sv + 1024, qkv, nullptr, flag, 1536);
    k_attn<<<dim3(16384), dim3(256), 0, stream>>>(qkv, sv + 5632, xw /*O*/);
    // proj: N=512, K=512 -> nbx=8, grid 2048
    k_gemm_bres<1,64,512><<<dim3(2048), dim3(256), 0, stream>>>(xw, wp_b, sv + 2560, x1, d_in[0], flag, 512);
    k_ln2<<<dim3(8192), dim3(256), 0, stream>>>(x1, sv + 3072, sv + 3584, xw /*h2*/);
    // fc1: N=1024, K=512 -> nbx=16, grid 4096
    k_gemm_bres<2,64,512><<<dim3(4096), dim3(256), 0, stream>>>(xw, w1_b, sv + 4096, qkv /*a*/, nullptr, flag, 1024);
    // fc2: N=512, K=1024 -> NTILE=32, nbx=16, grid 4096
    k_gemm_bres<3,32,1024><<<dim3(4096), dim3(256), 0, stream>>>(qkv, w2_b, sv + 5120, d_out, x1, flag, 512);
}

// Round 6
// 923.771 us; speedup vs baseline: 1.0088x; 1.0088x over previous
//
#include <hip/hip_runtime.h>
#include <hip/hip_bf16.h>
#include <math.h>

typedef __bf16 bf16_t;
typedef __bf16 bf16x8 __attribute__((ext_vector_type(8)));
typedef float f32x4 __attribute__((ext_vector_type(4)));

// ---------------------------------------------------------------------------
// Problem constants: B=4, H=64, W=128, C=512, F=1024, WS=4, SS=2, NH=8, hd=64.
// M = 32768 token rows. 2048 windows total.
// ---------------------------------------------------------------------------

#define X1_OFF   0u            // x1 fp32 residual [32768,512] = 64 MB
#define XW_OFF   67108864u     // xw -> O -> h2 (bf16, 32 MB)
#define QKV_OFF  100663296u    // qkv -> gelu-out a (bf16, 96 MB)
#define WQ_OFF   201326592u
#define WP_OFF   202899456u
#define W1_OFF   203423744u
#define W2_OFF   204472320u
#define SV_OFF   205520896u
#define FLAG_OFF 205545472u
// SV float offsets: g1=0 be1=512 bq=1024 bp=2560 g2=3072 be2=3584 b1=4096
//                   b2=5120 rpb=5632 (end 6024)

__device__ __forceinline__ int perm_row(int r) {
    int b   = r >> 13;
    int rem = r & 8191;
    int w   = rem >> 4;
    int n   = rem & 15;
    int wy  = w >> 5, wx = w & 31;
    int y   = wy * 4 + (n >> 2);
    int x   = wx * 4 + (n & 3);
    int ys  = (y + 2) & 63;
    int xs  = (x + 2) & 127;
    return (b << 13) + (ys << 7) + xs;
}

// global->LDS direct load, 16 B per lane: per-lane global addr, wave-uniform
// LDS base; HW scatters lane i -> base + i*16.
__device__ __forceinline__ void gld16(const void* g, void* l) {
    __builtin_amdgcn_global_load_lds(
        (const __attribute__((address_space(1))) unsigned int*)(unsigned long long)(uintptr_t)g,
        (__attribute__((address_space(3))) unsigned int*)(unsigned int)(uintptr_t)l,
        16, 0, 0);
}

// ---------------- dtype probe: 1 = fp32 source, 0 = bf16 source ----------------
__global__ __launch_bounds__(256) void k_probe(const unsigned short* __restrict__ x,
                                               int n, int* __restrict__ flag) {
    __shared__ int cnt;
    if (threadIdx.x == 0) cnt = 0;
    __syncthreads();
    int c = 0;
    for (int i = threadIdx.x; i < n; i += 256) {
        int e = (x[i] >> 7) & 0xFF;
        if (e >= 0xC0) c++;
    }
    atomicAdd(&cnt, c);
    __syncthreads();
    if (threadIdx.x == 0) *flag = (cnt > 8) ? 1 : 0;
}

// ---------------- weight / small-vector normalization ----------------
__global__ __launch_bounds__(256) void k_cvt_bf16(const void* __restrict__ src,
                                                  bf16_t* __restrict__ dst, int n,
                                                  const int* __restrict__ flag) {
    int i = blockIdx.x * 256 + threadIdx.x;
    if (i >= n) return;
    dst[i] = (*flag) ? (bf16_t)((const float*)src)[i] : ((const bf16_t*)src)[i];
}

__global__ __launch_bounds__(256) void k_cvt_small(
        const void* g1, const void* be1, const void* bq, const void* bp,
        const void* g2, const void* be2, const void* b1, const void* b2,
        const void* rpb, float* __restrict__ dst, const int* __restrict__ flag) {
    int i = blockIdx.x * 256 + threadIdx.x;
    const void* src; int off;
    if      (i < 512)  { src = g1;  off = i; }
    else if (i < 1024) { src = be1; off = i - 512; }
    else if (i < 2560) { src = bq;  off = i - 1024; }
    else if (i < 3072) { src = bp;  off = i - 2560; }
    else if (i < 3584) { src = g2;  off = i - 3072; }
    else if (i < 4096) { src = be2; off = i - 3584; }
    else if (i < 5120) { src = b1;  off = i - 4096; }
    else if (i < 5632) { src = b2;  off = i - 5120; }
    else if (i < 6024) { src = rpb; off = i - 5632; }
    else return;
    dst[i] = (*flag) ? ((const float*)src)[off] : (float)((const bf16_t*)src)[off];
}

// ---------------- Kernel 1: LN1 + shift + window partition ----------------
__global__ __launch_bounds__(256) void k_ln1(const void* __restrict__ x,
                                             const float* __restrict__ g,
                                             const float* __restrict__ be,
                                             bf16_t* __restrict__ xw,
                                             const int* __restrict__ flag) {
    int r    = blockIdx.x * 4 + (threadIdx.x >> 6);
    int lane = threadIdx.x & 63;
    int f    = *flag;
    long ro  = (long)perm_row(r) * 512;
    const float*  x32 = (const float*)x + ro;
    const bf16_t* x16 = (const bf16_t*)x + ro;
    int base = lane * 8;
    float v[8];
    float s = 0.f, ss = 0.f;
#pragma unroll
    for (int j = 0; j < 8; j++) {
        float t = f ? x32[base + j] : (float)x16[base + j];
        v[j] = t; s += t; ss += t * t;
    }
#pragma unroll
    for (int off = 32; off; off >>= 1) {
        s  += __shfl_down(s,  off, 64);
        ss += __shfl_down(ss, off, 64);
    }
    s  = __shfl(s, 0, 64);
    ss = __shfl(ss, 0, 64);
    float m   = s * (1.f / 512.f);
    float var = ss * (1.f / 512.f) - m * m;
    float inv = rsqrtf(var + 1e-5f);
    bf16_t* orow = xw + (long)r * 512;
#pragma unroll
    for (int j = 0; j < 8; j++)
        orow[base + j] = (bf16_t)((v[j] - m) * inv * g[base + j] + be[base + j]);
}

// ---------------- Kernel 5: LN2 ----------------
__global__ __launch_bounds__(256) void k_ln2(const float* __restrict__ x1,
                                             const float* __restrict__ g,
                                             const float* __restrict__ be,
                                             bf16_t* __restrict__ h2) {
    int r    = blockIdx.x * 4 + (threadIdx.x >> 6);
    int lane = threadIdx.x & 63;
    const float* xr = x1 + (long)r * 512;
    int base = lane * 8;
    float v[8];
    float s = 0.f, ss = 0.f;
#pragma unroll
    for (int j = 0; j < 8; j++) {
        float t = xr[base + j];
        v[j] = t; s += t; ss += t * t;
    }
#pragma unroll
    for (int off = 32; off; off >>= 1) {
        s  += __shfl_down(s,  off, 64);
        ss += __shfl_down(ss, off, 64);
    }
    s  = __shfl(s, 0, 64);
    ss = __shfl(ss, 0, 64);
    float m   = s * (1.f / 512.f);
    float var = ss * (1.f / 512.f) - m * m;
    float inv = rsqrtf(var + 1e-5f);
    bf16_t* orow = h2 + (long)r * 512;
#pragma unroll
    for (int j = 0; j < 8; j++)
        orow[base + j] = (bf16_t)((v[j] - m) * inv * g[base + j] + be[base + j]);
}

// ---------------- B-resident GEMM v2: dense-panel LDS + depth-4 A ring -----
// C = A @ W^T. A:[M,K] bf16 rm, global->VGPR with a 4-deep prefetch ring.
// W:[N,K] bf16 rm: whole [NTILE,KT] tile staged once into LDS as dense
// 128B-row panels: panel q (64 k-elems) holds rows of 8 16B chunks at
// position ppos = chunk ^ (row&7)  -> ds_read_b128 pattern identical to the
// round-4 measured-conflict-free one. One barrier total.
// Block = 128 x NTILE of C, 4 waves 2x2, quadrant 64 x NTILE/2.
// XCD swizzle: id%8 == row-stripe%8 -> A re-reads L2-local.
// EPI: 0=bias->bf16  1=proj: x1[perm]=x+acc+bias (fp32)  2=bias+GELU->bf16
//      3=fc2: out=x1+acc+bias (flag dtype)
template<int EPI, int NTILE, int KT>
__global__ __launch_bounds__(256) void k_gemm_bres(const bf16_t* __restrict__ A,
                                                   const bf16_t* __restrict__ Wt,
                                                   const float* __restrict__ bias,
                                                   void* __restrict__ out,
                                                   const void* __restrict__ res,
                                                   const int* __restrict__ flag,
                                                   int N) {
    constexpr int NF     = NTILE / 32;   // B-frags per wave per k-step (2 or 1)
    constexpr int KITERS = KT / 32;      // 16 or 32
    constexpr int PSZ    = NTILE * 64;   // elems per panel (4096 or 2048)
    constexpr int OCT    = NTILE / 8;    // row-octets per tile (8 or 4)
    __shared__ bf16_t sB[NTILE * KT];    // 64 KB

    int tid = threadIdx.x, lane = tid & 63, wv = tid >> 6;
    int nbx = N / NTILE;
    int id  = blockIdx.x;
    int xb  = (id >> 3) % nbx;
    int yb  = ((id >> 3) / nbx) * 8 + (id & 7);
    int m0  = yb << 7;
    int n0  = xb * NTILE;

    // ---- prologue: stage whole B tile (4096 chunks; 16 panel-octets/wave) --
#pragma unroll
    for (int j = 0; j < 16; j++) {
        int u  = j * 4 + wv;            // (panel, octet) pair, wave-uniform
        int o  = u % OCT, q = u / OCT;
        int r0 = o * 8;
        int row = r0 + (lane >> 3);
        int pin = (lane & 7) ^ (row & 7);
        const bf16_t* g = Wt + (long)(n0 + row) * KT + (q * 8 + pin) * 8;
        gld16(g, (char*)sB + ((long)q * PSZ + r0 * 64) * 2);
    }
    __syncthreads();   // the ONLY barrier

    int rr = lane & 15, quad = lane >> 4;
    int wm = (wv >> 1) * 64, wn = (wv & 1) * (NTILE / 2);

    const bf16_t* pA = A + (long)(m0 + wm + rr) * KT + quad * 8;

    f32x4 acc[4][NF];
#pragma unroll
    for (int mi = 0; mi < 4; mi++)
#pragma unroll
        for (int ni = 0; ni < NF; ni++) { f32x4 z = {0.f,0.f,0.f,0.f}; acc[mi][ni] = z; }

    // depth-4 A prefetch ring (slots 0..2 preloaded with kk=0..2)
    bf16x8 afn[4][4];
#pragma unroll
    for (int s = 0; s < 3; s++)
#pragma unroll
        for (int mi = 0; mi < 4; mi++)
            afn[s][mi] = *(const bf16x8*)(pA + (long)mi * 16 * KT + s * 32);

#pragma unroll
    for (int kk = 0; kk < KITERS; kk++) {
        int slot = kk & 3, pslot = (kk + 3) & 3;
        // prefetch kk+3 (unconditional; over-read stays inside ws - never used)
#pragma unroll
        for (int mi = 0; mi < 4; mi++)
            afn[pslot][mi] = *(const bf16x8*)(pA + (long)mi * 16 * KT + (kk + 3) * 32);
        // B fragments from dense panels
        bf16x8 bg[NF];
#pragma unroll
        for (int ni = 0; ni < NF; ni++) {
            int rl   = wn + ni * 16 + rr;
            int c    = kk * 4 + quad;
            int ppos = (c & 7) ^ (rl & 7);
            bg[ni] = *(const bf16x8*)(sB + (long)(c >> 3) * PSZ + rl * 64 + ppos * 8);
        }
#pragma unroll
        for (int mi = 0; mi < 4; mi++)
#pragma unroll
            for (int ni = 0; ni < NF; ni++)
                acc[mi][ni] = __builtin_amdgcn_mfma_f32_16x16x32_bf16(afn[slot][mi], bg[ni], acc[mi][ni], 0, 0, 0);
    }

    int f = (EPI == 1 || EPI == 3) ? *flag : 0;
#pragma unroll
    for (int ni = 0; ni < NF; ni++) {
        int col  = n0 + wn + ni * 16 + rr;
        float bb = bias[col];
#pragma unroll
        for (int mi = 0; mi < 4; mi++) {
#pragma unroll
            for (int i = 0; i < 4; i++) {
                int row  = m0 + wm + mi * 16 + quad * 4 + i;
                float v  = acc[mi][ni][i] + bb;
                if (EPI == 0) {
                    ((bf16_t*)out)[(long)row * N + col] = (bf16_t)v;
                } else if (EPI == 1) {
                    long o   = (long)perm_row(row) * 512 + col;
                    float xv = f ? ((const float*)res)[o] : (float)((const bf16_t*)res)[o];
                    ((float*)out)[o] = xv + v;
                } else if (EPI == 2) {
                    float ge = 0.5f * v * (1.f + erff(v * 0.70710678118654752f));
                    ((bf16_t*)out)[(long)row * N + col] = (bf16_t)ge;
                } else {
                    long o   = (long)row * 512 + col;
                    float vv = ((const float*)res)[o] + v;
                    if (f) ((float*)out)[o] = vv;
                    else   ((bf16_t*)out)[o] = (bf16_t)vv;
                }
            }
        }
    }
}

// ---------------- Kernel 3: windowed attention ----------------
__global__ __launch_bounds__(256) void k_attn(const bf16_t* __restrict__ qkv,
                                              const float* __restrict__ rpb,
                                              bf16_t* __restrict__ O) {
    __shared__ float q[16][68], k[16][68], v[16][68];
    __shared__ float S[16][17];

    int blk = blockIdx.x;
    int h   = blk & 7;
    int w   = blk >> 3;
    int tid = threadIdx.x;

    int n0 = tid >> 4;
    int d0 = (tid & 15) * 4;
    const bf16_t* base = qkv + (long)(w * 16 + n0) * 1536 + h * 64 + d0;
#pragma unroll
    for (int j = 0; j < 4; j++) {
        q[n0][d0 + j] = (float)base[j] * 0.125f;
        k[n0][d0 + j] = (float)base[512 + j];
        v[n0][d0 + j] = (float)base[1024 + j];
    }
    __syncthreads();

    int i = tid >> 4, j = tid & 15;
    float s = 0.f;
#pragma unroll
    for (int d = 0; d < 64; d++) s += q[i][d] * k[j][d];

    int iy = i >> 2, ix = i & 3, jy = j >> 2, jx = j & 3;
    s += rpb[((iy - jy + 3) * 7 + (ix - jx + 3)) * 8 + h];

    int wl = w & 511;
    int wy = wl >> 5, wx = wl & 31;
    int yi = wy * 4 + iy, xi = wx * 4 + ix;
    int yj = wy * 4 + jy, xj = wx * 4 + jx;
    int ri = (yi < 60 ? 0 : (yi < 62 ? 1 : 2)) * 3 + (xi < 124 ? 0 : (xi < 126 ? 1 : 2));
    int rj = (yj < 60 ? 0 : (yj < 62 ? 1 : 2)) * 3 + (xj < 124 ? 0 : (xj < 126 ? 1 : 2));
    if (ri != rj) s -= 100.f;
    S[i][j] = s;
    __syncthreads();

    if (tid < 16) {
        float mx = -1e30f;
#pragma unroll
        for (int c = 0; c < 16; c++) mx = fmaxf(mx, S[tid][c]);
        float sum = 0.f;
#pragma unroll
        for (int c = 0; c < 16; c++) { float e = expf(S[tid][c] - mx); S[tid][c] = e; sum += e; }
        float invs = 1.f / sum;
#pragma unroll
        for (int c = 0; c < 16; c++) S[tid][c] *= invs;
    }
    __syncthreads();

#pragma unroll
    for (int t = 0; t < 4; t++) {
        int e  = tid + t * 256;
        int oi = e >> 6, od = e & 63;
        float acc = 0.f;
#pragma unroll
        for (int c = 0; c < 16; c++) acc += S[oi][c] * v[c][od];
        O[(long)(w * 16 + oi) * 512 + h * 64 + od] = (bf16_t)acc;
    }
}

// ---------------------------------------------------------------------------
extern "C" void kernel_launch(void* const* d_in, const int* in_sizes, int n_in,
                              void* d_out, int out_size, void* d_ws, size_t ws_size,
                              hipStream_t stream) {
    char* ws = (char*)d_ws;
    float*  x1   = (float*)(ws + X1_OFF);
    bf16_t* xw   = (bf16_t*)(ws + XW_OFF);    // xw -> O -> h2
    bf16_t* qkv  = (bf16_t*)(ws + QKV_OFF);   // qkv -> gelu-out a
    bf16_t* wq_b = (bf16_t*)(ws + WQ_OFF);
    bf16_t* wp_b = (bf16_t*)(ws + WP_OFF);
    bf16_t* w1_b = (bf16_t*)(ws + W1_OFF);
    bf16_t* w2_b = (bf16_t*)(ws + W2_OFF);
    float*  sv   = (float*)(ws + SV_OFF);
    int*    flag = (int*)(ws + FLAG_OFF);

    k_probe<<<1, 256, 0, stream>>>((const unsigned short*)d_in[0], 4096, flag);
    k_cvt_bf16<<<3072, 256, 0, stream>>>(d_in[3],  wq_b, 786432, flag);
    k_cvt_bf16<<<1024, 256, 0, stream>>>(d_in[6],  wp_b, 262144, flag);
    k_cvt_bf16<<<2048, 256, 0, stream>>>(d_in[10], w1_b, 524288, flag);
    k_cvt_bf16<<<2048, 256, 0, stream>>>(d_in[12], w2_b, 524288, flag);
    k_cvt_small<<<24,  256, 0, stream>>>(d_in[1], d_in[2], d_in[4], d_in[7],
                                         d_in[8], d_in[9], d_in[11], d_in[13],
                                         d_in[5], sv, flag);

    k_ln1<<<dim3(8192), dim3(256), 0, stream>>>(d_in[0], sv, sv + 512, xw, flag);
    // qkv: M=32768, N=1536, K=512 -> nbx=24, grid 6144
    k_gemm_bres<0,64,512><<<dim3(6144), dim3(256), 0, stream>>>(xw, wq_b, sv + 1024, qkv, nullptr, flag, 1536);
    k_attn<<<dim3(16384), dim3(256), 0, stream>>>(qkv, sv + 5632, xw /*O*/);
    // proj: N=512, K=512 -> nbx=8, grid 2048
    k_gemm_bres<1,64,512><<<dim3(2048), dim3(256), 0, stream>>>(xw, wp_b, sv + 2560, x1, d_in[0], flag, 512);
    k_ln2<<<dim3(8192), dim3(256), 0, stream>>>(x1, sv + 3072, sv + 3584, xw /*h2*/);
    // fc1: N=1024, K=512 -> nbx=16, grid 4096
    k_gemm_bres<2,64,512><<<dim3(4096), dim3(256), 0, stream>>>(xw, w1_b, sv + 4096, qkv /*a*/, nullptr, flag, 1024);
    // fc2: N=512, K=1024 -> NTILE=32, nbx=16, grid 4096
    k_gemm_bres<3,32,1024><<<dim3(4096), dim3(256), 0, stream>>>(qkv, w2_b, sv + 5120, d_out, x1, flag, 512);
}